// Round 11
// baseline (176.668 us; speedup 1.0000x reference)
//
#include <hip/hip_runtime.h>
#include <hip/hip_bf16.h>

// PointNet2 FP: fused 3-NN + interp + concat + MLP(384->256->128), bf16 MFMA
#define BB 2
#define NN 16384
#define MM 4096
#define C1 128
#define C2 256
#define CIN 384
#define H1 256
#define H2 128
#define XROW 392       // 384 + 8 pad

typedef __attribute__((ext_vector_type(8))) short bf16x8;
typedef __attribute__((ext_vector_type(4))) float f32x4;
typedef __attribute__((ext_vector_type(2))) float f32x2;
typedef __attribute__((ext_vector_type(8))) float f32x8;

__device__ __forceinline__ short f32_to_bf16(float x) {
    unsigned u = __float_as_uint(x);
    u += 0x7fffu + ((u >> 16) & 1u);   // RNE
    return (short)(u >> 16);
}
__device__ __forceinline__ float bf16_to_f32(unsigned short u) {
    union { unsigned u; float f; } c; c.u = ((unsigned)u) << 16; return c.f;
}
__device__ __forceinline__ unsigned pack_bf16x2(float a, float b) {
    __hip_bfloat162 h = __float22bfloat162_rn(make_float2(a, b));
    union { __hip_bfloat162 h; unsigned u; } cv;
    cv.h = h;
    return cv.u;
}
// score pair: each op has exactly ONE sgpr-pair operand -> no s->v movs.
// MUST be used identically in pass A and pass B (bit-identical scores).
__device__ __forceinline__ f32x2 score2(f32x2 ax2, f32x2 ay2, f32x2 az2,
                                        f32x2 kx, f32x2 ky, f32x2 kz, f32x2 kn) {
    f32x2 t = ay2 * ky;
    t = __builtin_elementwise_fma(ax2, kx, t);
    t = __builtin_elementwise_fma(az2, kz, t);
    return t + kn;
}

// ---------------- Kernel 1: prep — transpose + weight cast + kpk ---------
__global__ __launch_bounds__(256) void prep_kernel(
    const float* __restrict__ KF, unsigned short* __restrict__ KT16,
    const float* __restrict__ W1, const float* __restrict__ W2,
    short* __restrict__ W1b, short* __restrict__ W2b,
    const float* __restrict__ known, float* __restrict__ kpk8)
{
    const int bx  = blockIdx.x;
    const int tid = threadIdx.x;
    if (bx < 2048) {
        __shared__ float tl[32][33];
        const int b  = bx >> 10;
        const int c0 = ((bx >> 7) & 7) * 32;
        const int m0 = (bx & 127) * 32;
        const int tx = tid & 31;
        const int ty = tid >> 5;            // 0..7
        #pragma unroll
        for (int r = 0; r < 4; ++r) {
            int c = ty + r * 8;
            tl[c][tx] = KF[((size_t)b * C2 + c0 + c) * MM + m0 + tx];
        }
        __syncthreads();
        #pragma unroll
        for (int r = 0; r < 4; ++r) {
            int m = ty + r * 8;
            KT16[((size_t)b * MM + m0 + m) * C2 + c0 + tx] =
                (unsigned short)f32_to_bf16(tl[tx][m]);
        }
    } else if (bx < 2432) {
        int i = (bx - 2048) * 256 + tid;
        if (i < H1 * CIN) W1b[i] = f32_to_bf16(W1[i]);
        if (i < H2 * H1)  W2b[i] = f32_to_bf16(W2[i]);
    } else {
        int i = (bx - 2432) * 256 + tid;
        if (i < BB * MM) {
            float x = known[3 * i + 0], y = known[3 * i + 1], z = known[3 * i + 2];
            float n = fmaf(x, x, fmaf(y, y, z * z));
            int g = i >> 1, j = i & 1;
            float* base = kpk8 + (size_t)g * 8;
            base[0 + j] = x; base[2 + j] = y; base[4 + j] = z; base[6 + j] = n;
        }
    }
}

// -------- Kernel 2: fused knn + gather-interp + 2-layer MFMA MLP ---------
// grid 512, block 512 (8 waves). Block owns 64 queries. LDS ~26.6 KB and
// 8 waves/block -> 4 blocks/CU = 32 waves (100% slots). Phase-1 scratch is
// unioned with the phase-2 X/H buffer; H aliases X after GEMM1 (acc in regs).
__global__ __launch_bounds__(512, 8) void fused_knn_mlp_kernel(
    const float* __restrict__ unknown,        // (B,N,3)
    const float* __restrict__ kpk8,           // packed candidate groups
    const float* __restrict__ unknow_feats,   // (B,C1,N)
    const unsigned short* __restrict__ KT16,  // (B,M,C2) bf16
    const short* __restrict__ W1b, const float* __restrict__ b1,
    const short* __restrict__ W2b, const float* __restrict__ b2,
    float* __restrict__ out)                  // (B,H2,N)
{
    union SharedU {
        struct {
            float pdv[8][64][3];
            float vf[64];
            float msc[64][8];
            int   mid[64][8];
            int   cnt[64];
        } p1;
        short XH[32][XROW];
    };
    __shared__ SharedU S;
    __shared__ int   IsL[64 * 3];
    __shared__ float WsL[64 * 3];

    const int bx    = blockIdx.x;             // 0..511
    const int tid   = threadIdx.x;
    const int lane  = tid & 63;
    const int w     = __builtin_amdgcn_readfirstlane(tid >> 6);  // 0..7
    const int b     = bx >> 8;
    const int qbase = (bx & 255) * 64;
    const int n     = qbase + lane;

    // ---- prefetch unknow_feats for both tiles (completes during knn) ----
    float4 uf[4];
    {
        const float* UFb = unknow_feats + (size_t)b * C1 * NN + qbase;
        #pragma unroll
        for (int i = 0; i < 4; ++i) {
            // tile = i>>1, half = i&1 ; element e in [0,1024) per tile
            int e  = (i & 1) * 512 + tid;
            int cc = e >> 3;                  // 0..127
            int nq = ((e & 7) << 2) + (i >> 1) * 32;   // point offset
            uf[i] = *(const float4*)(UFb + (size_t)cc * NN + nq);
        }
    }

    if (tid < 64) S.p1.cnt[tid] = 0;

    // ================= Phase 1: 3-NN for this block's 64 queries =========
    {
        const float ux = unknown[((size_t)b * NN + n) * 3 + 0];
        const float uy = unknown[((size_t)b * NN + n) * 3 + 1];
        const float uz = unknown[((size_t)b * NN + n) * 3 + 2];
        const f32x2 ax2 = {-2.f * ux, -2.f * ux};
        const f32x2 ay2 = {-2.f * uy, -2.f * uy};
        const f32x2 az2 = {-2.f * uz, -2.f * uz};
        const float un = fmaf(ux, ux, fmaf(uy, uy, uz * uz));

        const int gbase = w * 256;
        const float* __restrict__ kp = kpk8 + ((size_t)b * (MM / 2) + gbase) * 8;

        // Pass A: values-only top-3, dual accumulators
        float va0 = 3e38f, va1 = 3e38f, va2 = 3e38f;
        float vb0 = 3e38f, vb1 = 3e38f, vb2 = 3e38f;
        #pragma unroll 4
        for (int g = 0; g < 256; ++g) {
            const f32x8 G = *(const f32x8*)(kp + (size_t)g * 8);   // uniform
            const f32x2 kx = __builtin_shufflevector(G, G, 0, 1);
            const f32x2 ky = __builtin_shufflevector(G, G, 2, 3);
            const f32x2 kz = __builtin_shufflevector(G, G, 4, 5);
            const f32x2 kn = __builtin_shufflevector(G, G, 6, 7);
            const f32x2 sc2 = score2(ax2, ay2, az2, kx, ky, kz, kn);
            float sa = sc2.x;
            va2 = __builtin_amdgcn_fmed3f(va1, sa, va2);
            va1 = __builtin_amdgcn_fmed3f(va0, sa, va1);
            va0 = fminf(sa, va0);
            float sb = sc2.y;
            vb2 = __builtin_amdgcn_fmed3f(vb1, sb, vb2);
            vb1 = __builtin_amdgcn_fmed3f(vb0, sb, vb1);
            vb0 = fminf(sb, vb0);
        }
        {
            float bv[3] = {vb0, vb1, vb2};
            #pragma unroll
            for (int k = 0; k < 3; ++k) {
                float d = bv[k];
                va2 = __builtin_amdgcn_fmed3f(va1, d, va2);
                va1 = __builtin_amdgcn_fmed3f(va0, d, va1);
                va0 = fminf(d, va0);
            }
        }
        S.p1.pdv[w][lane][0] = va0; S.p1.pdv[w][lane][1] = va1; S.p1.pdv[w][lane][2] = va2;
        __syncthreads();

        if (tid < 64) {
            float r0 = 3e38f, r1 = 3e38f, r2 = 3e38f;
            #pragma unroll
            for (int ww = 0; ww < 8; ++ww) {
                #pragma unroll
                for (int k = 0; k < 3; ++k) {
                    float d = S.p1.pdv[ww][tid][k];
                    r2 = __builtin_amdgcn_fmed3f(r1, d, r2);
                    r1 = __builtin_amdgcn_fmed3f(r0, d, r1);
                    r0 = fminf(d, r0);
                }
            }
            S.p1.vf[tid] = r2;
        }
        __syncthreads();

        // Pass B: index recovery — identical score arithmetic
        const float v2f = S.p1.vf[lane];
        #pragma unroll 4
        for (int g = 0; g < 256; ++g) {
            const f32x8 G = *(const f32x8*)(kp + (size_t)g * 8);
            const f32x2 kx = __builtin_shufflevector(G, G, 0, 1);
            const f32x2 ky = __builtin_shufflevector(G, G, 2, 3);
            const f32x2 kz = __builtin_shufflevector(G, G, 4, 5);
            const f32x2 kn = __builtin_shufflevector(G, G, 6, 7);
            const f32x2 sc2 = score2(ax2, ay2, az2, kx, ky, kz, kn);
            if (fminf(sc2.x, sc2.y) <= v2f) {
                if (sc2.x <= v2f) {
                    int c = atomicAdd(&S.p1.cnt[lane], 1);
                    if (c < 8) { S.p1.msc[lane][c] = sc2.x; S.p1.mid[lane][c] = (gbase + g) * 2; }
                }
                if (sc2.y <= v2f) {
                    int c = atomicAdd(&S.p1.cnt[lane], 1);
                    if (c < 8) { S.p1.msc[lane][c] = sc2.y; S.p1.mid[lane][c] = (gbase + g) * 2 + 1; }
                }
            }
        }
        __syncthreads();

        if (tid < 64) {
            const int c = S.p1.cnt[tid] < 8 ? S.p1.cnt[tid] : 8;
            float r0 = 3e38f, r1 = 3e38f, r2 = 3e38f;
            int   q0 = 0x7FFFFFFF, q1 = 0x7FFFFFFF, q2 = 0x7FFFFFFF;
            #pragma unroll
            for (int k = 0; k < 8; ++k) {
                float d = (k < c) ? S.p1.msc[tid][k] : 3e38f;
                int   j = (k < c) ? S.p1.mid[tid][k] : 0x7FFFFFFF;
                const bool lt0 = (d < r0) || (d == r0 && j < q0);
                const bool lt1 = (d < r1) || (d == r1 && j < q1);
                const bool lt2 = (d < r2) || (d == r2 && j < q2);
                float nr2 = lt1 ? r1 : (lt2 ? d : r2);
                int   nq2 = lt1 ? q1 : (lt2 ? j : q2);
                float nr1 = lt0 ? r0 : (lt1 ? d : r1);
                int   nq1 = lt0 ? q0 : (lt1 ? j : q1);
                float nr0 = lt0 ? d : r0;
                int   nq0 = lt0 ? j : q0;
                r0 = nr0; r1 = nr1; r2 = nr2; q0 = nq0; q1 = nq1; q2 = nq2;
            }
            float d0 = sqrtf(fmaxf(r0 + un, 0.f));
            float d1 = sqrtf(fmaxf(r1 + un, 0.f));
            float d2 = sqrtf(fmaxf(r2 + un, 0.f));
            float i0 = 1.f / (d0 + 1e-8f);
            float i1 = 1.f / (d1 + 1e-8f);
            float i2 = 1.f / (d2 + 1e-8f);
            float s  = i0 + i1 + i2;
            IsL[tid * 3 + 0] = q0; IsL[tid * 3 + 1] = q1; IsL[tid * 3 + 2] = q2;
            WsL[tid * 3 + 0] = i0 / s; WsL[tid * 3 + 1] = i1 / s; WsL[tid * 3 + 2] = i2 / s;
        }
    }
    __syncthreads();   // phase-1 scratch dead; S.XH live from here

    // ================= Phase 2: MLP on this block's 64 points ============
    const unsigned short* KTb = KT16 + (size_t)b * MM * C2;
    const int lr = lane & 15;
    const int lq = lane >> 4;
    const int c4 = lane << 2;                    // 0..252

    for (int tile = 0; tile < 2; ++tile) {
        const int pbase = tile * 32;

        // ---- X build: wave w -> local points 4w..4w+3 ----
        {
            ushort4 g[4][3];
            #pragma unroll
            for (int j = 0; j < 4; ++j) {
                const int pi = (pbase + 4 * w + j) * 3;
                g[j][0] = *(const ushort4*)(KTb + (size_t)IsL[pi + 0] * C2 + c4);
                g[j][1] = *(const ushort4*)(KTb + (size_t)IsL[pi + 1] * C2 + c4);
                g[j][2] = *(const ushort4*)(KTb + (size_t)IsL[pi + 2] * C2 + c4);
            }
            // passthrough channels from the prefetched registers
            #pragma unroll
            for (int i = 0; i < 2; ++i) {
                const float4 f = uf[tile * 2 + i];
                int e  = i * 512 + tid;
                int cc = e >> 3;
                int nq = (e & 7) << 2;
                S.XH[nq + 0][C2 + cc] = f32_to_bf16(f.x);
                S.XH[nq + 1][C2 + cc] = f32_to_bf16(f.y);
                S.XH[nq + 2][C2 + cc] = f32_to_bf16(f.z);
                S.XH[nq + 3][C2 + cc] = f32_to_bf16(f.w);
            }
            #pragma unroll
            for (int j = 0; j < 4; ++j) {
                const int pl = 4 * w + j;
                const int pi = (pbase + pl) * 3;
                const float w0 = WsL[pi + 0], w1 = WsL[pi + 1], w2 = WsL[pi + 2];
                float vx = fmaf(w0, bf16_to_f32(g[j][0].x), fmaf(w1, bf16_to_f32(g[j][1].x), w2 * bf16_to_f32(g[j][2].x)));
                float vy = fmaf(w0, bf16_to_f32(g[j][0].y), fmaf(w1, bf16_to_f32(g[j][1].y), w2 * bf16_to_f32(g[j][2].y)));
                float vz = fmaf(w0, bf16_to_f32(g[j][0].z), fmaf(w1, bf16_to_f32(g[j][1].z), w2 * bf16_to_f32(g[j][2].z)));
                float vw = fmaf(w0, bf16_to_f32(g[j][0].w), fmaf(w1, bf16_to_f32(g[j][1].w), w2 * bf16_to_f32(g[j][2].w)));
                uint2 pk;
                pk.x = pack_bf16x2(vx, vy);
                pk.y = pack_bf16x2(vz, vw);
                *(uint2*)&S.XH[pl][c4] = pk;
            }
        }
        __syncthreads();

        // ---- GEMM1: wave w -> H1 rows [32w, 32w+32), 32 points ----
        f32x4 acc1[2][2];
        #pragma unroll
        for (int t = 0; t < 2; ++t)
            #pragma unroll
            for (int p = 0; p < 2; ++p) acc1[t][p] = (f32x4){0.f, 0.f, 0.f, 0.f};
        #pragma unroll 4
        for (int k0 = 0; k0 < CIN; k0 += 32) {
            bf16x8 a[2], x[2];
            #pragma unroll
            for (int t = 0; t < 2; ++t)
                a[t] = *(const bf16x8*)(W1b + (size_t)(w * 32 + t * 16 + lr) * CIN + k0 + lq * 8);
            #pragma unroll
            for (int p = 0; p < 2; ++p)
                x[p] = *(bf16x8*)&S.XH[p * 16 + lr][k0 + lq * 8];
            #pragma unroll
            for (int t = 0; t < 2; ++t)
                #pragma unroll
                for (int p = 0; p < 2; ++p)
                    acc1[t][p] = __builtin_amdgcn_mfma_f32_16x16x32_bf16(a[t], x[p], acc1[t][p], 0, 0, 0);
        }
        __syncthreads();   // X reads done — overwrite XH cols 0..255 with H

        #pragma unroll
        for (int t = 0; t < 2; ++t) {
            const int ob = w * 32 + t * 16 + lq * 4;
            float bb0 = b1[ob + 0], bb1 = b1[ob + 1], bb2 = b1[ob + 2], bb3 = b1[ob + 3];
            #pragma unroll
            for (int p = 0; p < 2; ++p) {
                uint2 pk;
                pk.x = pack_bf16x2(fmaxf(acc1[t][p].x + bb0, 0.f),
                                   fmaxf(acc1[t][p].y + bb1, 0.f));
                pk.y = pack_bf16x2(fmaxf(acc1[t][p].z + bb2, 0.f),
                                   fmaxf(acc1[t][p].w + bb3, 0.f));
                *(uint2*)&S.XH[p * 16 + lr][ob] = pk;
            }
        }
        __syncthreads();

        // ---- GEMM2: wave w -> H2 rows [16w, 16w+16), 32 points ----
        {
            f32x4 acc2[2];
            acc2[0] = (f32x4){0.f, 0.f, 0.f, 0.f};
            acc2[1] = (f32x4){0.f, 0.f, 0.f, 0.f};
            #pragma unroll 4
            for (int k0 = 0; k0 < H1; k0 += 32) {
                bf16x8 a2 = *(const bf16x8*)(W2b + (size_t)(w * 16 + lr) * H1 + k0 + lq * 8);
                bf16x8 h0 = *(bf16x8*)&S.XH[lr][k0 + lq * 8];
                bf16x8 h1 = *(bf16x8*)&S.XH[16 + lr][k0 + lq * 8];
                acc2[0] = __builtin_amdgcn_mfma_f32_16x16x32_bf16(a2, h0, acc2[0], 0, 0, 0);
                acc2[1] = __builtin_amdgcn_mfma_f32_16x16x32_bf16(a2, h1, acc2[1], 0, 0, 0);
            }
            #pragma unroll
            for (int p = 0; p < 2; ++p) {
                const int nn = qbase + pbase + p * 16 + lr;
                #pragma unroll
                for (int r = 0; r < 4; ++r) {
                    const int o = w * 16 + lq * 4 + r;
                    out[((size_t)b * H2 + o) * NN + nn] =
                        fmaxf(((const float*)&acc2[p])[r] + b2[o], 0.f);
                }
            }
        }
        __syncthreads();   // XH free for next tile
    }
}

extern "C" void kernel_launch(void* const* d_in, const int* in_sizes, int n_in,
                              void* d_out, int out_size, void* d_ws, size_t ws_size,
                              hipStream_t stream) {
    const float* unknown      = (const float*)d_in[0];
    const float* known        = (const float*)d_in[1];
    const float* unknow_feats = (const float*)d_in[2];
    const float* known_feats  = (const float*)d_in[3];
    const float* W1           = (const float*)d_in[4];
    const float* b1           = (const float*)d_in[5];
    const float* W2           = (const float*)d_in[6];
    const float* b2           = (const float*)d_in[7];
    float* out = (float*)d_out;

    char* ws = (char*)d_ws;
    short*          W1b  = (short*)(ws);                    // 196608 B
    short*          W2b  = (short*)(ws + 196608);           // 65536 B
    float*          kpk8 = (float*)(ws + 262144);           // 131072 B
    unsigned short* KT16 = (unsigned short*)(ws + 393216);  // 4194304 B

    prep_kernel<<<2464, 256, 0, stream>>>(
        known_feats, KT16, W1, W2, W1b, W2b, known, kpk8);

    fused_knn_mlp_kernel<<<512, 512, 0, stream>>>(
        unknown, kpk8, unknow_feats, KT16, W1b, b1, W2b, b2, out);
}

// Round 12
// 163.858 us; speedup vs baseline: 1.0782x; 1.0782x over previous
//
#include <hip/hip_runtime.h>
#include <hip/hip_bf16.h>

// PointNet2 FP: fused 3-NN + interp + concat + MLP(384->256->128), bf16 MFMA
#define BB 2
#define NN 16384
#define MM 4096
#define C1 128
#define C2 256
#define CIN 384
#define H1 256
#define H2 128
#define XROW 392       // 384 + 8 pad
#define HROW 264       // 256 + 8 pad

typedef __attribute__((ext_vector_type(8))) short bf16x8;
typedef __attribute__((ext_vector_type(4))) float f32x4;
typedef __attribute__((ext_vector_type(2))) float f32x2;
typedef __attribute__((ext_vector_type(8))) float f32x8;

__device__ __forceinline__ short f32_to_bf16(float x) {
    unsigned u = __float_as_uint(x);
    u += 0x7fffu + ((u >> 16) & 1u);   // RNE
    return (short)(u >> 16);
}
__device__ __forceinline__ float bf16_to_f32(unsigned short u) {
    union { unsigned u; float f; } c; c.u = ((unsigned)u) << 16; return c.f;
}
__device__ __forceinline__ unsigned pack_bf16x2(float a, float b) {
    __hip_bfloat162 h = __float22bfloat162_rn(make_float2(a, b));
    union { __hip_bfloat162 h; unsigned u; } cv;
    cv.h = h;
    return cv.u;
}
// score pair: each op has exactly ONE sgpr-pair operand -> no s->v movs.
// MUST be used identically in pass A and pass B (bit-identical scores).
__device__ __forceinline__ f32x2 score2(f32x2 ax2, f32x2 ay2, f32x2 az2,
                                        f32x2 kx, f32x2 ky, f32x2 kz, f32x2 kn) {
    f32x2 t = ay2 * ky;
    t = __builtin_elementwise_fma(ax2, kx, t);
    t = __builtin_elementwise_fma(az2, kz, t);
    return t + kn;
}

// ---------------- Kernel 1: prep — transpose + weight cast + kpk ---------
__global__ __launch_bounds__(256) void prep_kernel(
    const float* __restrict__ KF, unsigned short* __restrict__ KT16,
    const float* __restrict__ W1, const float* __restrict__ W2,
    short* __restrict__ W1b, short* __restrict__ W2b,
    const float* __restrict__ known, float* __restrict__ kpk8)
{
    const int bx  = blockIdx.x;
    const int tid = threadIdx.x;
    if (bx < 2048) {
        __shared__ float tl[32][33];
        const int b  = bx >> 10;
        const int c0 = ((bx >> 7) & 7) * 32;
        const int m0 = (bx & 127) * 32;
        const int tx = tid & 31;
        const int ty = tid >> 5;            // 0..7
        #pragma unroll
        for (int r = 0; r < 4; ++r) {
            int c = ty + r * 8;
            tl[c][tx] = KF[((size_t)b * C2 + c0 + c) * MM + m0 + tx];
        }
        __syncthreads();
        #pragma unroll
        for (int r = 0; r < 4; ++r) {
            int m = ty + r * 8;
            KT16[((size_t)b * MM + m0 + m) * C2 + c0 + tx] =
                (unsigned short)f32_to_bf16(tl[tx][m]);
        }
    } else if (bx < 2432) {
        int i = (bx - 2048) * 256 + tid;
        if (i < H1 * CIN) W1b[i] = f32_to_bf16(W1[i]);
        if (i < H2 * H1)  W2b[i] = f32_to_bf16(W2[i]);
    } else {
        int i = (bx - 2432) * 256 + tid;
        if (i < BB * MM) {
            float x = known[3 * i + 0], y = known[3 * i + 1], z = known[3 * i + 2];
            float n = fmaf(x, x, fmaf(y, y, z * z));
            int g = i >> 1, j = i & 1;
            float* base = kpk8 + (size_t)g * 8;
            base[0 + j] = x; base[2 + j] = y; base[4 + j] = z; base[6 + j] = n;
        }
    }
}

// -------- Kernel 2: fused knn + gather-interp + 2-layer MFMA MLP ---------
// grid 512, block 1024 (16 waves) -> 2 blocks/CU = 32 waves (full slots).
// Block owns 64 queries. Latency-hiding: unknow_feats prefetched at entry
// (covered by knn); tile-1 feature gathers issued during tile-0 GEMMs.
__global__ __launch_bounds__(1024, 8) void fused_knn_mlp_kernel(
    const float* __restrict__ unknown,        // (B,N,3)
    const float* __restrict__ kpk8,           // packed candidate groups
    const float* __restrict__ unknow_feats,   // (B,C1,N)
    const unsigned short* __restrict__ KT16,  // (B,M,C2) bf16
    const short* __restrict__ W1b, const float* __restrict__ b1,
    const short* __restrict__ W2b, const float* __restrict__ b2,
    float* __restrict__ out)                  // (B,H2,N)
{
    __shared__ float pdv[16][64][3];
    __shared__ float vf[64];
    __shared__ float msc[64][8];
    __shared__ int   mid[64][8];
    __shared__ int   cnt[64];
    __shared__ int   IsL[64 * 3];
    __shared__ float WsL[64 * 3];
    __shared__ short XH[32][XROW];
    __shared__ short Hs[32][HROW];

    const int bx    = blockIdx.x;             // 0..511
    const int tid   = threadIdx.x;
    const int lane  = tid & 63;
    const int w     = __builtin_amdgcn_readfirstlane(tid >> 6);  // 0..15
    const int b     = bx >> 8;
    const int qbase = (bx & 255) * 64;
    const int n     = qbase + lane;

    // ---- prefetch unknow_feats for both tiles (completes during knn) ----
    // per tile: C1*32/4 = 1024 float4 loads, one per thread
    float4 uf[2];
    {
        const float* UFb = unknow_feats + (size_t)b * C1 * NN + qbase;
        const int cc = tid >> 3;              // 0..127
        const int nq = (tid & 7) << 2;        // 0,4,..,28
        #pragma unroll
        for (int t = 0; t < 2; ++t)
            uf[t] = *(const float4*)(UFb + (size_t)cc * NN + t * 32 + nq);
    }

    if (tid < 64) cnt[tid] = 0;

    // ================= Phase 1: 3-NN for this block's 64 queries =========
    {
        const float ux = unknown[((size_t)b * NN + n) * 3 + 0];
        const float uy = unknown[((size_t)b * NN + n) * 3 + 1];
        const float uz = unknown[((size_t)b * NN + n) * 3 + 2];
        const f32x2 ax2 = {-2.f * ux, -2.f * ux};
        const f32x2 ay2 = {-2.f * uy, -2.f * uy};
        const f32x2 az2 = {-2.f * uz, -2.f * uz};
        const float un = fmaf(ux, ux, fmaf(uy, uy, uz * uz));

        const int gbase = w * 128;
        const float* __restrict__ kp = kpk8 + ((size_t)b * (MM / 2) + gbase) * 8;

        // Pass A: values-only top-3, dual accumulators
        float va0 = 3e38f, va1 = 3e38f, va2 = 3e38f;
        float vb0 = 3e38f, vb1 = 3e38f, vb2 = 3e38f;
        #pragma unroll 4
        for (int g = 0; g < 128; ++g) {
            const f32x8 G = *(const f32x8*)(kp + (size_t)g * 8);   // uniform
            const f32x2 kx = __builtin_shufflevector(G, G, 0, 1);
            const f32x2 ky = __builtin_shufflevector(G, G, 2, 3);
            const f32x2 kz = __builtin_shufflevector(G, G, 4, 5);
            const f32x2 kn = __builtin_shufflevector(G, G, 6, 7);
            const f32x2 sc2 = score2(ax2, ay2, az2, kx, ky, kz, kn);
            float sa = sc2.x;
            va2 = __builtin_amdgcn_fmed3f(va1, sa, va2);
            va1 = __builtin_amdgcn_fmed3f(va0, sa, va1);
            va0 = fminf(sa, va0);
            float sb = sc2.y;
            vb2 = __builtin_amdgcn_fmed3f(vb1, sb, vb2);
            vb1 = __builtin_amdgcn_fmed3f(vb0, sb, vb1);
            vb0 = fminf(sb, vb0);
        }
        {
            float bv[3] = {vb0, vb1, vb2};
            #pragma unroll
            for (int k = 0; k < 3; ++k) {
                float d = bv[k];
                va2 = __builtin_amdgcn_fmed3f(va1, d, va2);
                va1 = __builtin_amdgcn_fmed3f(va0, d, va1);
                va0 = fminf(d, va0);
            }
        }
        pdv[w][lane][0] = va0; pdv[w][lane][1] = va1; pdv[w][lane][2] = va2;
        __syncthreads();

        if (tid < 64) {
            float r0 = 3e38f, r1 = 3e38f, r2 = 3e38f;
            #pragma unroll
            for (int ww = 0; ww < 16; ++ww) {
                #pragma unroll
                for (int k = 0; k < 3; ++k) {
                    float d = pdv[ww][tid][k];
                    r2 = __builtin_amdgcn_fmed3f(r1, d, r2);
                    r1 = __builtin_amdgcn_fmed3f(r0, d, r1);
                    r0 = fminf(d, r0);
                }
            }
            vf[tid] = r2;
        }
        __syncthreads();

        // Pass B: index recovery — identical score arithmetic
        const float v2f = vf[lane];
        #pragma unroll 4
        for (int g = 0; g < 128; ++g) {
            const f32x8 G = *(const f32x8*)(kp + (size_t)g * 8);
            const f32x2 kx = __builtin_shufflevector(G, G, 0, 1);
            const f32x2 ky = __builtin_shufflevector(G, G, 2, 3);
            const f32x2 kz = __builtin_shufflevector(G, G, 4, 5);
            const f32x2 kn = __builtin_shufflevector(G, G, 6, 7);
            const f32x2 sc2 = score2(ax2, ay2, az2, kx, ky, kz, kn);
            if (fminf(sc2.x, sc2.y) <= v2f) {
                if (sc2.x <= v2f) {
                    int c = atomicAdd(&cnt[lane], 1);
                    if (c < 8) { msc[lane][c] = sc2.x; mid[lane][c] = (gbase + g) * 2; }
                }
                if (sc2.y <= v2f) {
                    int c = atomicAdd(&cnt[lane], 1);
                    if (c < 8) { msc[lane][c] = sc2.y; mid[lane][c] = (gbase + g) * 2 + 1; }
                }
            }
        }
        __syncthreads();

        if (tid < 64) {
            const int c = cnt[tid] < 8 ? cnt[tid] : 8;
            float r0 = 3e38f, r1 = 3e38f, r2 = 3e38f;
            int   q0 = 0x7FFFFFFF, q1 = 0x7FFFFFFF, q2 = 0x7FFFFFFF;
            #pragma unroll
            for (int k = 0; k < 8; ++k) {
                float d = (k < c) ? msc[tid][k] : 3e38f;
                int   j = (k < c) ? mid[tid][k] : 0x7FFFFFFF;
                const bool lt0 = (d < r0) || (d == r0 && j < q0);
                const bool lt1 = (d < r1) || (d == r1 && j < q1);
                const bool lt2 = (d < r2) || (d == r2 && j < q2);
                float nr2 = lt1 ? r1 : (lt2 ? d : r2);
                int   nq2 = lt1 ? q1 : (lt2 ? j : q2);
                float nr1 = lt0 ? r0 : (lt1 ? d : r1);
                int   nq1 = lt0 ? q0 : (lt1 ? j : q1);
                float nr0 = lt0 ? d : r0;
                int   nq0 = lt0 ? j : q0;
                r0 = nr0; r1 = nr1; r2 = nr2; q0 = nq0; q1 = nq1; q2 = nq2;
            }
            float d0 = sqrtf(fmaxf(r0 + un, 0.f));
            float d1 = sqrtf(fmaxf(r1 + un, 0.f));
            float d2 = sqrtf(fmaxf(r2 + un, 0.f));
            float i0 = 1.f / (d0 + 1e-8f);
            float i1 = 1.f / (d1 + 1e-8f);
            float i2 = 1.f / (d2 + 1e-8f);
            float s  = i0 + i1 + i2;
            IsL[tid * 3 + 0] = q0; IsL[tid * 3 + 1] = q1; IsL[tid * 3 + 2] = q2;
            WsL[tid * 3 + 0] = i0 / s; WsL[tid * 3 + 1] = i1 / s; WsL[tid * 3 + 2] = i2 / s;
        }
    }
    __syncthreads();

    // ================= Phase 2: MLP on this block's 64 points ============
    const unsigned short* KTb = KT16 + (size_t)b * MM * C2;
    const int lr = lane & 15;
    const int lq = lane >> 4;
    const int c4 = lane << 2;                    // 0..252

    // prologue: issue tile-0 gathers (wave w -> local points 2w, 2w+1)
    ushort4 gcur[2][3], gnext[2][3];
    #pragma unroll
    for (int j = 0; j < 2; ++j) {
        const int pi = (2 * w + j) * 3;
        gcur[j][0] = *(const ushort4*)(KTb + (size_t)IsL[pi + 0] * C2 + c4);
        gcur[j][1] = *(const ushort4*)(KTb + (size_t)IsL[pi + 1] * C2 + c4);
        gcur[j][2] = *(const ushort4*)(KTb + (size_t)IsL[pi + 2] * C2 + c4);
    }

    for (int tile = 0; tile < 2; ++tile) {
        const int pbase = tile * 32;

        // ---- X build from prefetched registers ----
        {
            #pragma unroll
            for (int j = 0; j < 2; ++j) {
                const int pl = 2 * w + j;
                const int pi = (pbase + pl) * 3;
                const float w0 = WsL[pi + 0], w1 = WsL[pi + 1], w2 = WsL[pi + 2];
                float vx = fmaf(w0, bf16_to_f32(gcur[j][0].x), fmaf(w1, bf16_to_f32(gcur[j][1].x), w2 * bf16_to_f32(gcur[j][2].x)));
                float vy = fmaf(w0, bf16_to_f32(gcur[j][0].y), fmaf(w1, bf16_to_f32(gcur[j][1].y), w2 * bf16_to_f32(gcur[j][2].y)));
                float vz = fmaf(w0, bf16_to_f32(gcur[j][0].z), fmaf(w1, bf16_to_f32(gcur[j][1].z), w2 * bf16_to_f32(gcur[j][2].z)));
                float vw = fmaf(w0, bf16_to_f32(gcur[j][0].w), fmaf(w1, bf16_to_f32(gcur[j][1].w), w2 * bf16_to_f32(gcur[j][2].w)));
                uint2 pk;
                pk.x = pack_bf16x2(vx, vy);
                pk.y = pack_bf16x2(vz, vw);
                *(uint2*)&XH[pl][c4] = pk;
            }
            const float4 f = uf[tile];
            const int cc = tid >> 3;
            const int nq = (tid & 7) << 2;
            XH[nq + 0][C2 + cc] = f32_to_bf16(f.x);
            XH[nq + 1][C2 + cc] = f32_to_bf16(f.y);
            XH[nq + 2][C2 + cc] = f32_to_bf16(f.z);
            XH[nq + 3][C2 + cc] = f32_to_bf16(f.w);
        }
        __syncthreads();

        // ---- issue tile-1 gathers now; they complete during the GEMMs ----
        if (tile == 0) {
            #pragma unroll
            for (int j = 0; j < 2; ++j) {
                const int pi = (32 + 2 * w + j) * 3;
                gnext[j][0] = *(const ushort4*)(KTb + (size_t)IsL[pi + 0] * C2 + c4);
                gnext[j][1] = *(const ushort4*)(KTb + (size_t)IsL[pi + 1] * C2 + c4);
                gnext[j][2] = *(const ushort4*)(KTb + (size_t)IsL[pi + 2] * C2 + c4);
            }
        }

        // ---- GEMM1: wave w -> H1 rows [16w, 16w+16), 32 points ----
        f32x4 acc1[2];
        acc1[0] = (f32x4){0.f, 0.f, 0.f, 0.f};
        acc1[1] = (f32x4){0.f, 0.f, 0.f, 0.f};
        #pragma unroll 4
        for (int k0 = 0; k0 < CIN; k0 += 32) {
            bf16x8 a  = *(const bf16x8*)(W1b + (size_t)(w * 16 + lr) * CIN + k0 + lq * 8);
            bf16x8 x0 = *(bf16x8*)&XH[lr][k0 + lq * 8];
            bf16x8 x1 = *(bf16x8*)&XH[16 + lr][k0 + lq * 8];
            acc1[0] = __builtin_amdgcn_mfma_f32_16x16x32_bf16(a, x0, acc1[0], 0, 0, 0);
            acc1[1] = __builtin_amdgcn_mfma_f32_16x16x32_bf16(a, x1, acc1[1], 0, 0, 0);
        }
        {
            const int ob = w * 16 + lq * 4;
            float bb0 = b1[ob + 0], bb1 = b1[ob + 1], bb2 = b1[ob + 2], bb3 = b1[ob + 3];
            #pragma unroll
            for (int p = 0; p < 2; ++p) {
                uint2 pk;
                pk.x = pack_bf16x2(fmaxf(acc1[p].x + bb0, 0.f),
                                   fmaxf(acc1[p].y + bb1, 0.f));
                pk.y = pack_bf16x2(fmaxf(acc1[p].z + bb2, 0.f),
                                   fmaxf(acc1[p].w + bb3, 0.f));
                *(uint2*)&Hs[p * 16 + lr][ob] = pk;
            }
        }
        __syncthreads();

        // ---- GEMM2: wave w -> H2 rows [16(w&7),+16), points [16(w>>3),+16)
        {
            const int r0 = (w & 7) * 16;
            const int pg = (w >> 3) * 16;
            f32x4 acc2 = (f32x4){0.f, 0.f, 0.f, 0.f};
            #pragma unroll 4
            for (int k0 = 0; k0 < H1; k0 += 32) {
                bf16x8 a2 = *(const bf16x8*)(W2b + (size_t)(r0 + lr) * H1 + k0 + lq * 8);
                bf16x8 h  = *(bf16x8*)&Hs[pg + lr][k0 + lq * 8];
                acc2 = __builtin_amdgcn_mfma_f32_16x16x32_bf16(a2, h, acc2, 0, 0, 0);
            }
            const int nn = qbase + pbase + pg + lr;
            #pragma unroll
            for (int r = 0; r < 4; ++r) {
                const int o = r0 + lq * 4 + r;
                out[((size_t)b * H2 + o) * NN + nn] =
                    fmaxf(((const float*)&acc2)[r] + b2[o], 0.f);
            }
        }
        __syncthreads();   // Hs/XH free for next tile

        #pragma unroll
        for (int j = 0; j < 2; ++j)
            #pragma unroll
            for (int k = 0; k < 3; ++k) gcur[j][k] = gnext[j][k];
    }
}

extern "C" void kernel_launch(void* const* d_in, const int* in_sizes, int n_in,
                              void* d_out, int out_size, void* d_ws, size_t ws_size,
                              hipStream_t stream) {
    const float* unknown      = (const float*)d_in[0];
    const float* known        = (const float*)d_in[1];
    const float* unknow_feats = (const float*)d_in[2];
    const float* known_feats  = (const float*)d_in[3];
    const float* W1           = (const float*)d_in[4];
    const float* b1           = (const float*)d_in[5];
    const float* W2           = (const float*)d_in[6];
    const float* b2           = (const float*)d_in[7];
    float* out = (float*)d_out;

    char* ws = (char*)d_ws;
    short*          W1b  = (short*)(ws);                    // 196608 B
    short*          W2b  = (short*)(ws + 196608);           // 65536 B
    float*          kpk8 = (float*)(ws + 262144);           // 131072 B
    unsigned short* KT16 = (unsigned short*)(ws + 393216);  // 4194304 B

    prep_kernel<<<2464, 256, 0, stream>>>(
        known_feats, KT16, W1, W2, W1b, W2b, known, kpk8);

    fused_knn_mlp_kernel<<<512, 1024, 0, stream>>>(
        unknown, kpk8, unknow_feats, KT16, W1b, b1, W2b, b2, out);
}